// Round 3
// baseline (127.572 us; speedup 1.0000x reference)
//
#include <hip/hip_runtime.h>

#define BATCH   8
#define SHAPE_N 8192
#define SKEL_M  2048

// ---------------------------------------------------------------------------
// Per-direction worker: each thread owns 4 A-points (registers, 4 independent
// min chains); block scans a 256-point B-chunk staged in LDS (float4 ->
// ds_read_b128 broadcast, conflict-free). Partial mins merged across B-chunks
// via atomicMin on uint bits of d^2 (nonneg floats: bit order == numeric).
// ---------------------------------------------------------------------------
template <int SA, int SB, int NA, int NB>
__device__ __forceinline__ void cd_dir(
    const float* __restrict__ A, const float* __restrict__ B,
    unsigned int* __restrict__ ws, int b, int a0, int c0, int tid,
    float4* sB)
{
    // stage B chunk
    {
        const float* q = B + ((size_t)b * NB + c0 + tid) * SB;
        sB[tid] = make_float4(q[0], q[1], q[2], 0.f);
    }

    const float* Ab = A + (size_t)b * NA * SA;
    float ax[4], ay[4], az[4], dmin[4];
#pragma unroll
    for (int k = 0; k < 4; ++k) {
        const float* p = Ab + (size_t)(a0 + k * 256 + tid) * SA;
        ax[k] = p[0]; ay[k] = p[1]; az[k] = p[2];
        dmin[k] = 3.4e38f;
    }
    __syncthreads();

#pragma unroll 8
    for (int i = 0; i < 256; ++i) {
        float4 q = sB[i];
#pragma unroll
        for (int k = 0; k < 4; ++k) {
            float dx = ax[k] - q.x, dy = ay[k] - q.y, dz = az[k] - q.z;
            float d2 = dx * dx + dy * dy + dz * dz;
            dmin[k] = fminf(dmin[k], d2);
        }
    }

    unsigned int* wsb = ws + (size_t)b * NA;
#pragma unroll
    for (int k = 0; k < 4; ++k)
        atomicMin(&wsb[a0 + k * 256 + tid], __float_as_uint(dmin[k]));
}

// ---------------------------------------------------------------------------
// Fused kernel: blocks [0,512) do shape->skel, [512,1024) do skel->shape.
// 1024 blocks = 4 blocks/CU = 4 waves/SIMD; branch is block-uniform.
// dir1: b = bid>>6, ablk = (bid&63)>>3 (8 of 1024 pts), chunk = bid&7   (8x256)
// dir2: b = j>>6,   ablk = (j&63)>>5   (2 of 1024 pts), chunk = j&31    (32x256)
// ---------------------------------------------------------------------------
__global__ __launch_bounds__(256) void cd_main(
    const float* __restrict__ shape, const float* __restrict__ skel,
    unsigned int* __restrict__ ws)
{
    __shared__ float4 sB[256];
    const int tid = threadIdx.x;
    const int bid = blockIdx.x;
    if (bid < 512) {
        const int b = bid >> 6, rem = bid & 63;
        cd_dir<6, 3, SHAPE_N, SKEL_M>(shape, skel, ws,
                                      b, (rem >> 3) * 1024, (rem & 7) * 256, tid, sB);
    } else {
        const int j = bid - 512;
        const int b = j >> 6, rem = j & 63;
        cd_dir<3, 6, SKEL_M, SHAPE_N>(skel, shape, ws + (size_t)BATCH * SHAPE_N,
                                      b, (rem >> 5) * 1024, (rem & 31) * 256, tid, sB);
    }
}

// ---------------------------------------------------------------------------
// Finalize: ONE block of 1024 threads sqrt+sums all 81920 mins and WRITES
// out[0] (no atomic, no pre-zero of d_out needed).
// ---------------------------------------------------------------------------
__global__ __launch_bounds__(1024) void cd_finalize(
    const unsigned int* __restrict__ ws, float* __restrict__ out)
{
    __shared__ float s_wsum[16];
    float s = 0.f;
    for (int i = threadIdx.x; i < BATCH * (SHAPE_N + SKEL_M); i += 1024)
        s += sqrtf(__uint_as_float(ws[i]));
    for (int off = 32; off; off >>= 1) s += __shfl_down(s, off, 64);
    const int lane = threadIdx.x & 63, wave = threadIdx.x >> 6;
    if (lane == 0) s_wsum[wave] = s;
    __syncthreads();
    if (threadIdx.x == 0) {
        float t = 0.f;
#pragma unroll
        for (int w = 0; w < 16; ++w) t += s_wsum[w];
        out[0] = t * 1e-4f;
    }
}

extern "C" void kernel_launch(void* const* d_in, const int* in_sizes, int n_in,
                              void* d_out, int out_size, void* d_ws, size_t ws_size,
                              hipStream_t stream) {
    const float* shape = (const float*)d_in[0];   // (8, 8192, 6) — use first 3
    const float* skel  = (const float*)d_in[1];   // (8, 2048, 3)
    float* out         = (float*)d_out;           // scalar
    unsigned int* ws   = (unsigned int*)d_ws;     // 81920 uints = 320 KB

    hipMemsetAsync(ws, 0xFF,
                   (size_t)BATCH * (SHAPE_N + SKEL_M) * sizeof(unsigned int),
                   stream);
    cd_main<<<1024, 256, 0, stream>>>(shape, skel, ws);
    cd_finalize<<<1, 1024, 0, stream>>>(ws, out);
}

// Round 4
// 84.355 us; speedup vs baseline: 1.5123x; 1.5123x over previous
//
#include <hip/hip_runtime.h>

#define BATCH   8
#define SHAPE_N 8192
#define SKEL_M  2048

// ---------------------------------------------------------------------------
// Per-direction worker. d2 = |a|^2 + |b|^2 - 2 a.b  (the reference's own
// expansion). LDS B-chunk staged as (-2bx, -2by, -2bz, |b|^2); each thread
// owns 4 A-points with precomputed ra=|a|^2. Inner pair = add + 3 fma + min
// = 5 VALU. Cross-chunk merge: atomicMin on uint bits of max(d2,0)
// (nonneg floats: IEEE bit order == numeric order).
// ---------------------------------------------------------------------------
template <int SA, int SB, int NA, int NB>
__device__ __forceinline__ void cd_dir(
    const float* __restrict__ A, const float* __restrict__ B,
    unsigned int* __restrict__ ws, int b, int a0, int c0, int tid,
    float4* sB)
{
    // stage B chunk as (-2b, |b|^2)
    {
        const float* q = B + ((size_t)b * NB + c0 + tid) * SB;
        const float qx = q[0], qy = q[1], qz = q[2];
        sB[tid] = make_float4(-2.f * qx, -2.f * qy, -2.f * qz,
                              qx * qx + qy * qy + qz * qz);
    }

    const float* Ab = A + (size_t)b * NA * SA;
    float ax[4], ay[4], az[4], ra[4], dmin[4];
#pragma unroll
    for (int k = 0; k < 4; ++k) {
        const float* p = Ab + (size_t)(a0 + k * 256 + tid) * SA;
        ax[k] = p[0]; ay[k] = p[1]; az[k] = p[2];
        ra[k] = ax[k] * ax[k] + ay[k] * ay[k] + az[k] * az[k];
        dmin[k] = 3.4e38f;
    }
    __syncthreads();

#pragma unroll 8
    for (int i = 0; i < 256; ++i) {
        float4 q = sB[i];
#pragma unroll
        for (int k = 0; k < 4; ++k) {
            float t = ra[k] + q.w;          // |a|^2 + |b|^2
            t = fmaf(ax[k], q.x, t);        // -2*ax*bx + ...
            t = fmaf(ay[k], q.y, t);
            t = fmaf(az[k], q.z, t);
            dmin[k] = fminf(dmin[k], t);
        }
    }

    unsigned int* wsb = ws + (size_t)b * NA;
#pragma unroll
    for (int k = 0; k < 4; ++k)
        atomicMin(&wsb[a0 + k * 256 + tid],
                  __float_as_uint(fmaxf(dmin[k], 0.f)));
}

// ---------------------------------------------------------------------------
// Fused kernel: blocks [0,512) shape->skel, [512,1024) skel->shape.
// Block 0 thread 0 also zeroes out[0] (visible to cd_finalize via stream
// order; finalize is the only reader/writer of out afterwards).
// ---------------------------------------------------------------------------
__global__ __launch_bounds__(256) void cd_main(
    const float* __restrict__ shape, const float* __restrict__ skel,
    unsigned int* __restrict__ ws, float* __restrict__ out)
{
    __shared__ float4 sB[256];
    const int tid = threadIdx.x;
    const int bid = blockIdx.x;
    if (bid == 0 && tid == 0) out[0] = 0.f;
    if (bid < 512) {
        const int b = bid >> 6, rem = bid & 63;
        cd_dir<6, 3, SHAPE_N, SKEL_M>(shape, skel, ws,
                                      b, (rem >> 3) * 1024, (rem & 7) * 256, tid, sB);
    } else {
        const int j = bid - 512;
        const int b = j >> 6, rem = j & 63;
        cd_dir<3, 6, SKEL_M, SHAPE_N>(skel, shape, ws + (size_t)BATCH * SHAPE_N,
                                      b, (rem >> 5) * 1024, (rem & 31) * 256, tid, sB);
    }
}

// ---------------------------------------------------------------------------
// Finalize: 80 blocks x 256 thr; each thread sqrt+sums 4 mins (uint4 load),
// wave/block reduce, one atomicAdd per block into out (zeroed by cd_main).
// ---------------------------------------------------------------------------
__global__ __launch_bounds__(256) void cd_finalize(
    const uint4* __restrict__ ws, float* __restrict__ out)
{
    __shared__ float s_wsum[4];
    const uint4 v = ws[blockIdx.x * 256 + threadIdx.x];
    float s = sqrtf(__uint_as_float(v.x)) + sqrtf(__uint_as_float(v.y)) +
              sqrtf(__uint_as_float(v.z)) + sqrtf(__uint_as_float(v.w));
    for (int off = 32; off; off >>= 1) s += __shfl_down(s, off, 64);
    const int lane = threadIdx.x & 63, wave = threadIdx.x >> 6;
    if (lane == 0) s_wsum[wave] = s;
    __syncthreads();
    if (threadIdx.x == 0) {
        atomicAdd(out, (s_wsum[0] + s_wsum[1] + s_wsum[2] + s_wsum[3]) * 1e-4f);
    }
}

extern "C" void kernel_launch(void* const* d_in, const int* in_sizes, int n_in,
                              void* d_out, int out_size, void* d_ws, size_t ws_size,
                              hipStream_t stream) {
    const float* shape = (const float*)d_in[0];   // (8, 8192, 6) — use first 3
    const float* skel  = (const float*)d_in[1];   // (8, 2048, 3)
    float* out         = (float*)d_out;           // scalar
    unsigned int* ws   = (unsigned int*)d_ws;     // 81920 uints = 320 KB

    hipMemsetAsync(ws, 0xFF,
                   (size_t)BATCH * (SHAPE_N + SKEL_M) * sizeof(unsigned int),
                   stream);
    cd_main<<<1024, 256, 0, stream>>>(shape, skel, ws, out);
    cd_finalize<<<BATCH * (SHAPE_N + SKEL_M) / 1024, 256, 0, stream>>>(
        (const uint4*)ws, out);
}